// Round 1
// baseline (298.660 us; speedup 1.0000x reference)
//
#include <hip/hip_runtime.h>

// ---------------------------------------------------------------------------
// FCGF_point_att2_ican_fc: per-point score -> global BN(1) -> per-segment
// softmax attention pooling -> FC(32,64) -> BN(64).
//
// N = 1,048,576 points x 32 feats (128 MiB fp32), B = 64 segments.
// Two unavoidable passes over x (softmax weights depend on global z-stats).
// x fits in 256 MiB L3, so pass 2 should be Infinity-Cache-fed.
//
// Pipeline (all on `stream`, graph-capture safe):
//   memset(ws accumulators) ->
//   k_stats  : pass 1 over x, per-block double partials of (sum z, sum z^2)
//   k_consts : reduce partials -> c1 = g1*rsqrt(var+eps), c2 = beta1-c1*mu,
//              prefix-sum of segment lengths
//   k_pool   : pass 2 over x, e = exp(s), accumulate (sum e*x, sum e) per seg
//   k_head   : pooled = num/(den*len); h = pooled@W2+b2; BN over 64 rows; out
// ---------------------------------------------------------------------------

#define EPS 1e-5f
#define NSB 2048          // stat blocks in k_stats (8 per CU)

// workspace layout (bytes)
#define WS_DPART   0          // double[2*NSB]            = 32768 B
#define WS_CONSTS  32768      // float c1, c2
#define WS_OFFS    32800      // int[65] segment offsets
#define WS_GNUM    33280      // float[64*32] sum(e*x)
#define WS_GDEN    41472      // float[64]    sum(e)
#define WS_ZERO_OFF 33280
#define WS_ZERO_SZ  8448      // gnum + gden

// ---------------------------------------------------------------------------
// Pass 1: per-row z = x.w1 + b1; accumulate sum(z), sum(z^2) in double.
// 8 lanes per row: lane q loads float4 of feats [4q,4q+3] (fully coalesced:
// 256 consecutive lanes -> 4 KB contiguous), butterfly-reduce over 8 lanes.
__global__ __launch_bounds__(256) void k_stats(const float* __restrict__ x,
                                               const float* __restrict__ w1,
                                               const float* __restrict__ b1,
                                               int N, int rpb,
                                               double* __restrict__ dpart) {
    const int tid = threadIdx.x;
    const int q = tid & 7;
    const float4 w4 = ((const float4*)w1)[q];
    const float b1v = b1[0];
    const float4* __restrict__ xv = (const float4*)x;
    const int row0 = blockIdx.x * rpb;
    const int iters = (rpb + 31) >> 5;

    double accZ = 0.0, accZZ = 0.0;
    for (int it = 0; it < iters; ++it) {
        int row = row0 + it * 32 + (tid >> 3);
        if (row < N) {
            float4 v = xv[row * 8 + q];
            float zp = v.x * w4.x + v.y * w4.y + v.z * w4.z + v.w * w4.w;
            // butterfly within the 8-lane group (rows uniform per group)
            zp += __shfl_xor(zp, 1);
            zp += __shfl_xor(zp, 2);
            zp += __shfl_xor(zp, 4);
            if (q == 0) {
                float z = zp + b1v;
                accZ  += (double)z;
                accZZ += (double)z * (double)z;
            }
        }
    }

    __shared__ double sZ[256], sZZ[256];
    sZ[tid] = accZ; sZZ[tid] = accZZ;
    __syncthreads();
    for (int s = 128; s > 0; s >>= 1) {
        if (tid < s) { sZ[tid] += sZ[tid + s]; sZZ[tid] += sZZ[tid + s]; }
        __syncthreads();
    }
    if (tid == 0) {
        dpart[2 * blockIdx.x]     = sZ[0];
        dpart[2 * blockIdx.x + 1] = sZZ[0];
    }
}

// ---------------------------------------------------------------------------
// Reduce the NSB double partials -> mu, var -> c1, c2; prefix-sum lengths.
__global__ __launch_bounds__(256) void k_consts(const double* __restrict__ dpart,
                                                const int* __restrict__ length,
                                                const float* __restrict__ g1,
                                                const float* __restrict__ beta1,
                                                int N, int B,
                                                float* __restrict__ consts,
                                                int* __restrict__ offs) {
    __shared__ double sZ[256], sZZ[256];
    const int tid = threadIdx.x;
    double aZ = 0.0, aZZ = 0.0;
    for (int i = tid; i < NSB; i += 256) {
        aZ  += dpart[2 * i];
        aZZ += dpart[2 * i + 1];
    }
    sZ[tid] = aZ; sZZ[tid] = aZZ;
    __syncthreads();
    for (int s = 128; s > 0; s >>= 1) {
        if (tid < s) { sZ[tid] += sZ[tid + s]; sZZ[tid] += sZZ[tid + s]; }
        __syncthreads();
    }
    if (tid == 0) {
        double mu  = sZ[0] / (double)N;
        double var = sZZ[0] / (double)N - mu * mu;
        float c1 = (float)((double)g1[0] / sqrt(var + (double)EPS));
        float c2 = beta1[0] - (float)(c1 * mu);
        consts[0] = c1;
        consts[1] = c2;
        int o = 0;
        offs[0] = 0;
        for (int b = 0; b < B; ++b) { o += length[b]; offs[b + 1] = o; }
    }
}

// ---------------------------------------------------------------------------
// Pass 2: per-row s = (c1*z + c2) * rowsum * (1/32); e = exp(s) (segment-max
// subtraction skipped: s in ~[-2,2], exactly equivalent after normalization).
// Accumulate per-segment sum(e*x) (32 feats) and sum(e).
// Grid: (chunks=32, seg=B) -> each block is inside exactly one segment.
__global__ __launch_bounds__(256) void k_pool(const float* __restrict__ x,
                                              const float* __restrict__ w1,
                                              const float* __restrict__ b1,
                                              const float* __restrict__ consts,
                                              const int* __restrict__ offs,
                                              float* __restrict__ gnum,
                                              float* __restrict__ gden) {
    const int tid = threadIdx.x;
    const int q = tid & 7;
    const int b = blockIdx.y;
    const int off = offs[b];
    const int len = offs[b + 1] - off;
    const int nch = gridDim.x;
    const int rpc = (len + nch - 1) / nch;
    const int r0 = blockIdx.x * rpc;
    const int r1 = min(r0 + rpc, len);

    const float4 w4 = ((const float4*)w1)[q];
    const float b1v = b1[0];
    const float c1 = consts[0], c2 = consts[1];
    const float4* __restrict__ xv = (const float4*)x;

    float4 acc = make_float4(0.f, 0.f, 0.f, 0.f);
    float accE = 0.f;

    for (int r = r0 + (tid >> 3); r < r1; r += 32) {
        int row = off + r;
        float4 v = xv[row * 8 + q];
        float zp = v.x * w4.x + v.y * w4.y + v.z * w4.z + v.w * w4.w;
        float rp = v.x + v.y + v.z + v.w;
        zp += __shfl_xor(zp, 1);  rp += __shfl_xor(rp, 1);
        zp += __shfl_xor(zp, 2);  rp += __shfl_xor(rp, 2);
        zp += __shfl_xor(zp, 4);  rp += __shfl_xor(rp, 4);
        float z = zp + b1v;
        float s = (c1 * z + c2) * rp * 0.03125f;
        float e = __expf(s);
        acc.x += e * v.x; acc.y += e * v.y; acc.z += e * v.z; acc.w += e * v.w;
        if (q == 0) accE += e;
    }

    // wave-level reduce across the 8 lane-groups (same features live on
    // lanes q, q+8, ..., q+56); accE is nonzero only on q==0 lanes.
    for (int m = 8; m <= 32; m <<= 1) {
        acc.x += __shfl_xor(acc.x, m);
        acc.y += __shfl_xor(acc.y, m);
        acc.z += __shfl_xor(acc.z, m);
        acc.w += __shfl_xor(acc.w, m);
        accE  += __shfl_xor(accE, m);
    }
    const int lane = tid & 63;
    if (lane < 8) {
        atomicAdd(&gnum[b * 32 + lane * 4 + 0], acc.x);
        atomicAdd(&gnum[b * 32 + lane * 4 + 1], acc.y);
        atomicAdd(&gnum[b * 32 + lane * 4 + 2], acc.z);
        atomicAdd(&gnum[b * 32 + lane * 4 + 3], acc.w);
        if (lane == 0) atomicAdd(&gden[b], accE);
    }
}

// ---------------------------------------------------------------------------
// Epilogue: pooled = num/(den*len); h = pooled @ W2 + b2; BN over B rows.
__global__ __launch_bounds__(256) void k_head(const float* __restrict__ gnum,
                                              const float* __restrict__ gden,
                                              const int* __restrict__ length,
                                              const float* __restrict__ W2,
                                              const float* __restrict__ b2,
                                              const float* __restrict__ g2,
                                              const float* __restrict__ beta2,
                                              float* __restrict__ out, int B) {
    __shared__ float pooled[64 * 32];
    __shared__ float h[64 * 64];
    __shared__ float mu2[64], isd[64];
    const int tid = threadIdx.x;

    for (int i = tid; i < B * 32; i += 256) {
        int bb = i >> 5;
        pooled[i] = gnum[i] / (gden[bb] * (float)length[bb]);
    }
    __syncthreads();

    const int j = tid & 63;       // output feature
    const int g = tid >> 6;       // 0..3 row group
    for (int r = 0; r < 16; ++r) {
        int bb = g * 16 + r;
        if (bb < B) {
            float hv = b2[j];
            for (int k = 0; k < 32; ++k) hv += pooled[bb * 32 + k] * W2[k * 64 + j];
            h[bb * 64 + j] = hv;
        }
    }
    __syncthreads();

    if (tid < 64) {
        float m = 0.f;
        for (int bb = 0; bb < B; ++bb) m += h[bb * 64 + tid];
        m /= (float)B;
        float v = 0.f;
        for (int bb = 0; bb < B; ++bb) { float d = h[bb * 64 + tid] - m; v += d * d; }
        v /= (float)B;
        mu2[tid] = m;
        isd[tid] = rsqrtf(v + EPS);
    }
    __syncthreads();

    for (int r = 0; r < 16; ++r) {
        int bb = g * 16 + r;
        if (bb < B) {
            int idx = bb * 64 + j;
            out[idx] = g2[j] * (h[idx] - mu2[j]) * isd[j] + beta2[j];
        }
    }
}

// ---------------------------------------------------------------------------
extern "C" void kernel_launch(void* const* d_in, const int* in_sizes, int n_in,
                              void* d_out, int out_size, void* d_ws, size_t ws_size,
                              hipStream_t stream) {
    const float* x      = (const float*)d_in[0];
    const int*   length = (const int*)  d_in[1];
    const float* w1     = (const float*)d_in[2];
    const float* b1     = (const float*)d_in[3];
    const float* g1     = (const float*)d_in[4];
    const float* beta1  = (const float*)d_in[5];
    const float* W2     = (const float*)d_in[6];
    const float* b2     = (const float*)d_in[7];
    const float* g2     = (const float*)d_in[8];
    const float* beta2  = (const float*)d_in[9];
    float* out = (float*)d_out;

    const int N = in_sizes[0] / 32;
    const int B = in_sizes[1];

    char* ws = (char*)d_ws;
    double* dpart  = (double*)(ws + WS_DPART);
    float*  consts = (float*) (ws + WS_CONSTS);
    int*    offs   = (int*)   (ws + WS_OFFS);
    float*  gnum   = (float*) (ws + WS_GNUM);
    float*  gden   = (float*) (ws + WS_GDEN);

    hipMemsetAsync(ws + WS_ZERO_OFF, 0, WS_ZERO_SZ, stream);

    int rpb = (N + NSB - 1) / NSB;
    rpb = (rpb + 31) & ~31;   // multiple of 32 rows per block

    k_stats <<<NSB, 256, 0, stream>>>(x, w1, b1, N, rpb, dpart);
    k_consts<<<1,   256, 0, stream>>>(dpart, length, g1, beta1, N, B, consts, offs);
    k_pool  <<<dim3(32, B), 256, 0, stream>>>(x, w1, b1, consts, offs, gnum, gden);
    k_head  <<<1,   256, 0, stream>>>(gnum, gden, length, W2, b2, g2, beta2, out, B);
}